// Round 2
// baseline (201.504 us; speedup 1.0000x reference)
//
#include <hip/hip_runtime.h>
#include <math.h>

// Exact-path rewrite: per (b,d) 4096-pt double-precision FFT -> f32-replicated
// Gaussian mask (even-symmetrized, has Nyquist derivative-kink => 1/tau^2 FIR
// tails, which killed the round-0 short-FIR approach) -> double inverse FFT.
// Two d-series packed into one complex FFT (mask real+even => Re/Im separate).

#define NTH 256
#define PHYS(i) ((i) + ((i) >> 4))

// ---------------- table setup kernel ----------------
__device__ __forceinline__ float mask_f32(int k, int j) {
  // replicate: freqs=fftfreq(4096).astype(f32) (exact), centers f32, /0.2f, **2, *-0.5f, expf
  float f = (float)((j < 2048) ? j : (j - 4096)) * (1.0f / 4096.0f);
  float c = ((float)k - 2.5f) / 5.0f;
  float df = fabsf(f - c);
  float q = df / 0.2f;
  return expf(-0.5f * (q * q));
}

__global__ void tables_k(double2* __restrict__ Wt, double* __restrict__ Mdr) {
  int j = blockIdx.x * NTH + threadIdx.x;   // 0..4095
  double ang = -(2.0 * 3.14159265358979323846 / 4096.0) * (double)j;
  Wt[j] = make_double2(cos(ang), sin(ang));
  int jr = (int)(__brev((unsigned)j) >> 20);      // bitrev12
  int jrn = (4096 - jr) & 4095;
#pragma unroll
  for (int k = 0; k < 5; ++k) {
    float m1 = mask_f32(k, jr);
    float m2 = mask_f32(k, jrn);
    // even-symmetrized mask (exact in f64) with ifft 1/N folded in
    Mdr[k * 4096 + j] = ((double)m1 + (double)m2) * (0.5 / 4096.0);
  }
}

// ---------------- transpose (B,T,D) -> (B,D,T) ----------------
__global__ void transpose_k(const float* __restrict__ x, float* __restrict__ xT) {
  __shared__ float tile[64][65];
  int bb = blockIdx.x >> 6;
  int tt = blockIdx.x & 63;
  int lane = threadIdx.x & 63;
  int grp = threadIdx.x >> 6;
#pragma unroll
  for (int r = 0; r < 16; ++r) {
    int tl = grp + 4 * r;
    tile[tl][lane] = x[((size_t)bb * 4096 + tt * 64 + tl) * 64 + lane];
  }
  __syncthreads();
#pragma unroll
  for (int r = 0; r < 16; ++r) {
    int dl = grp + 4 * r;
    xT[((size_t)bb * 64 + dl) * 4096 + tt * 64 + lane] = tile[lane][dl];
  }
}

// ---------------- FFT building blocks ----------------
template <int S, bool INV>
__device__ __forceinline__ void fft_stage(double* __restrict__ SRe, double* __restrict__ SIm,
                                          const double2* __restrict__ Wt, int tid) {
  const int LOG = 9 - 3 * S;
  const int sub = 1 << LOG;
#pragma unroll
  for (int gi = 0; gi < 2; ++gi) {
    const int g = tid + 256 * gi;
    const int b_hi = g >> LOG;
    const int b_lo = g & (sub - 1);
    const int base = b_hi * (sub << 3) + b_lo;
    int idx[8];
    double ar[8], ai[8];
#pragma unroll
    for (int q = 0; q < 8; ++q) {
      idx[q] = PHYS(base + q * sub);
      ar[q] = SRe[idx[q]];
      ai[q] = SIm[idx[q]];
    }
    double2 t1[4], t2[2], t3;
#pragma unroll
    for (int q = 0; q < 4; ++q) t1[q] = Wt[(b_lo + q * sub) << (3 * S)];
    t2[0] = Wt[b_lo << (3 * S + 1)];
    t2[1] = Wt[(b_lo + sub) << (3 * S + 1)];
    t3 = Wt[b_lo << (3 * S + 2)];
    if (!INV) {
#pragma unroll
      for (int q = 0; q < 4; ++q) {
        double ur = ar[q] - ar[q + 4], ui = ai[q] - ai[q + 4];
        ar[q] += ar[q + 4]; ai[q] += ai[q + 4];
        ar[q + 4] = ur * t1[q].x - ui * t1[q].y;
        ai[q + 4] = ur * t1[q].y + ui * t1[q].x;
      }
#pragma unroll
      for (int h = 0; h < 8; h += 4)
#pragma unroll
        for (int qq = 0; qq < 2; ++qq) {
          int q = h + qq;
          double ur = ar[q] - ar[q + 2], ui = ai[q] - ai[q + 2];
          ar[q] += ar[q + 2]; ai[q] += ai[q + 2];
          ar[q + 2] = ur * t2[qq].x - ui * t2[qq].y;
          ai[q + 2] = ur * t2[qq].y + ui * t2[qq].x;
        }
#pragma unroll
      for (int q = 0; q < 8; q += 2) {
        double ur = ar[q] - ar[q + 1], ui = ai[q] - ai[q + 1];
        ar[q] += ar[q + 1]; ai[q] += ai[q + 1];
        ar[q + 1] = ur * t3.x - ui * t3.y;
        ai[q + 1] = ur * t3.y + ui * t3.x;
      }
    } else {
#pragma unroll
      for (int q = 0; q < 8; q += 2) {
        double br = ar[q + 1] * t3.x + ai[q + 1] * t3.y;
        double bi = ai[q + 1] * t3.x - ar[q + 1] * t3.y;
        ar[q + 1] = ar[q] - br; ai[q + 1] = ai[q] - bi;
        ar[q] += br; ai[q] += bi;
      }
#pragma unroll
      for (int h = 0; h < 8; h += 4)
#pragma unroll
        for (int qq = 0; qq < 2; ++qq) {
          int q = h + qq;
          double br = ar[q + 2] * t2[qq].x + ai[q + 2] * t2[qq].y;
          double bi = ai[q + 2] * t2[qq].x - ar[q + 2] * t2[qq].y;
          ar[q + 2] = ar[q] - br; ai[q + 2] = ai[q] - bi;
          ar[q] += br; ai[q] += bi;
        }
#pragma unroll
      for (int q = 0; q < 4; ++q) {
        double br = ar[q + 4] * t1[q].x + ai[q + 4] * t1[q].y;
        double bi = ai[q + 4] * t1[q].x - ar[q + 4] * t1[q].y;
        ar[q + 4] = ar[q] - br; ai[q + 4] = ai[q] - bi;
        ar[q] += br; ai[q] += bi;
      }
    }
#pragma unroll
    for (int q = 0; q < 8; ++q) { SRe[idx[q]] = ar[q]; SIm[idx[q]] = ai[q]; }
  }
}

// s=3 group (sub=1, b_lo=0), register-resident, on 8 elements
__device__ __forceinline__ void s3_fwd(double* ar, double* ai, const double2* __restrict__ Wt) {
  double2 t1[4];
#pragma unroll
  for (int q = 0; q < 4; ++q) t1[q] = Wt[q << 9];
  double2 t20 = Wt[0], t21 = Wt[1 << 10];
#pragma unroll
  for (int q = 0; q < 4; ++q) {
    double ur = ar[q] - ar[q + 4], ui = ai[q] - ai[q + 4];
    ar[q] += ar[q + 4]; ai[q] += ai[q + 4];
    ar[q + 4] = ur * t1[q].x - ui * t1[q].y;
    ai[q + 4] = ur * t1[q].y + ui * t1[q].x;
  }
#pragma unroll
  for (int h = 0; h < 8; h += 4)
#pragma unroll
    for (int qq = 0; qq < 2; ++qq) {
      int q = h + qq;
      double2 t = qq ? t21 : t20;
      double ur = ar[q] - ar[q + 2], ui = ai[q] - ai[q + 2];
      ar[q] += ar[q + 2]; ai[q] += ai[q + 2];
      ar[q + 2] = ur * t.x - ui * t.y;
      ai[q + 2] = ur * t.y + ui * t.x;
    }
#pragma unroll
  for (int q = 0; q < 8; q += 2) {  // twiddle = W^0 = 1
    double ur = ar[q] - ar[q + 1], ui = ai[q] - ai[q + 1];
    ar[q] += ar[q + 1]; ai[q] += ai[q + 1];
    ar[q + 1] = ur; ai[q + 1] = ui;
  }
}

__device__ __forceinline__ void s3_inv(double* ar, double* ai, const double2* __restrict__ Wt) {
  double2 t1[4];
#pragma unroll
  for (int q = 0; q < 4; ++q) t1[q] = Wt[q << 9];
  double2 t20 = Wt[0], t21 = Wt[1 << 10];
#pragma unroll
  for (int q = 0; q < 8; q += 2) {
    double br = ar[q + 1], bi = ai[q + 1];
    ar[q + 1] = ar[q] - br; ai[q + 1] = ai[q] - bi;
    ar[q] += br; ai[q] += bi;
  }
#pragma unroll
  for (int h = 0; h < 8; h += 4)
#pragma unroll
    for (int qq = 0; qq < 2; ++qq) {
      int q = h + qq;
      double2 t = qq ? t21 : t20;
      double br = ar[q + 2] * t.x + ai[q + 2] * t.y;
      double bi = ai[q + 2] * t.x - ar[q + 2] * t.y;
      ar[q + 2] = ar[q] - br; ai[q + 2] = ai[q] - bi;
      ar[q] += br; ai[q] += bi;
    }
#pragma unroll
  for (int q = 0; q < 4; ++q) {
    double br = ar[q + 4] * t1[q].x + ai[q + 4] * t1[q].y;
    double bi = ai[q + 4] * t1[q].x - ar[q + 4] * t1[q].y;
    ar[q + 4] = ar[q] - br; ai[q + 4] = ai[q] - bi;
    ar[q] += br; ai[q] += bi;
  }
}

__device__ __forceinline__ void corr_write(float* o, const float* st, int j) {
  const int k = (int)((440700928u >> (3 * j)) & 7u);
  const int l = (int)((611428561u >> (3 * j)) & 7u);
  const float Sk = st[k], Sl = st[l];
  const int offk = (k * (11 - k)) >> 1;
  const int offl = (l * (11 - l)) >> 1;
  const float Skl = st[5 + offk + (l - k)];
  const float Skk = st[5 + offk];
  const float Sll = st[5 + offl];
  const float invT = 1.0f / 4096.0f;
  float cov = Skl - Sk * Sl * invT;
  float vk = Skk - Sk * Sk * invT;
  float vl = Sll - Sl * Sl * invT;
  float dk = sqrtf(fmaxf(vk, 0.f)), dl = sqrtf(fmaxf(vl, 0.f));
  float den = dk * dl;
  float corr = den > 0.f ? cov / den : 0.f;
  o[36 + j] = fminf(1.f, fmaxf(-1.f, corr));
}

// ---------------- main kernel: one block per (b, d-pair) ----------------
#define SMEM_BYTES 90880

__global__ __launch_bounds__(NTH, 1) void tf_main(const float* __restrict__ x,
                                                  const float* __restrict__ xT, int use_xt,
                                                  const double2* __restrict__ Wt,
                                                  const double* __restrict__ Mdr,
                                                  float* __restrict__ out) {
  extern __shared__ double smem[];
  double* SRe = smem;                 // 4352
  double* SIm = smem + 4352;          // 4352
  unsigned char* hist = (unsigned char*)(smem + 8704);  // 256*76 = 19456 B
  float* red = (float*)(hist + 19456);                  // 160
  float* stats = red + 160;                             // 40
  unsigned int* histf = (unsigned int*)(stats + 40);    // 72
  float* rowinv = (float*)(histf + 72);                 // 12

  const int tid = threadIdx.x;
  const int beta = blockIdx.x;
  const int b = beta >> 5;
  const int dA = (beta & 31) * 2;

  {  // zero own hist slice (76 B, dword-aligned)
    unsigned int* hw = (unsigned int*)(hist + tid * 76);
#pragma unroll
    for (int i = 0; i < 19; ++i) hw[i] = 0u;
  }

  // ---- stage x (two series -> complex) ----
  if (use_xt) {
    const float4* ra = (const float4*)(xT + (size_t)(b * 64 + dA) * 4096);
    const float4* rb = (const float4*)(xT + (size_t)(b * 64 + dA + 1) * 4096);
    for (int t4 = tid; t4 < 1024; t4 += NTH) {
      float4 va = ra[t4], vb = rb[t4];
      int t = t4 * 4;
      SRe[PHYS(t)] = (double)va.x;     SIm[PHYS(t)] = (double)vb.x;
      SRe[PHYS(t + 1)] = (double)va.y; SIm[PHYS(t + 1)] = (double)vb.y;
      SRe[PHYS(t + 2)] = (double)va.z; SIm[PHYS(t + 2)] = (double)vb.z;
      SRe[PHYS(t + 3)] = (double)va.w; SIm[PHYS(t + 3)] = (double)vb.w;
    }
  } else {
    const float2* xp = (const float2*)(x + (size_t)b * 4096 * 64 + dA);
    for (int t = tid; t < 4096; t += NTH) {
      float2 v = xp[(size_t)t * 32];
      SRe[PHYS(t)] = (double)v.x;
      SIm[PHYS(t)] = (double)v.y;
    }
  }
  __syncthreads();

  // ---- forward FFT: stages s=0..2 in LDS, s=3 in regs ----
  fft_stage<0, false>(SRe, SIm, Wt, tid); __syncthreads();
  fft_stage<1, false>(SRe, SIm, Wt, tid); __syncthreads();
  fft_stage<2, false>(SRe, SIm, Wt, tid); __syncthreads();

  double Fr[16], Fi[16];
#pragma unroll
  for (int j = 0; j < 16; ++j) {
    int p = PHYS(tid * 16 + j);
    Fr[j] = SRe[p]; Fi[j] = SIm[p];
  }
  s3_fwd(&Fr[0], &Fi[0], Wt);
  s3_fwd(&Fr[8], &Fi[8], Wt);
  // Fr/Fi now hold spectrum at bit-reversed slots [16*tid, 16*tid+16)

  float eA[80], eB[80];

#pragma unroll
  for (int k = 0; k < 5; ++k) {
    double Zr[16], Zi[16];
#pragma unroll
    for (int j = 0; j < 16; ++j) {
      double m = Mdr[k * 4096 + tid * 16 + j];
      Zr[j] = Fr[j] * m; Zi[j] = Fi[j] * m;
    }
    s3_inv(&Zr[0], &Zi[0], Wt);
    s3_inv(&Zr[8], &Zi[8], Wt);
    __syncthreads();  // previous band's readers done before overwrite
#pragma unroll
    for (int j = 0; j < 16; ++j) {
      int p = PHYS(tid * 16 + j);
      SRe[p] = Zr[j]; SIm[p] = Zi[j];
    }
    __syncthreads();
    fft_stage<2, true>(SRe, SIm, Wt, tid); __syncthreads();
    fft_stage<1, true>(SRe, SIm, Wt, tid); __syncthreads();
    fft_stage<0, true>(SRe, SIm, Wt, tid); __syncthreads();
    // SRe[t] = modes_a[t], SIm[t] = modes_b[t] (natural order, double)

    // ---- band pass: ordinal patterns + energy stash ----
    {
      const int t0 = tid * 16;
      double a0 = SRe[PHYS(t0)], a1 = SRe[PHYS(t0 + 1)];
      double c0 = SIm[PHYS(t0)], c1 = SIm[PHYS(t0 + 1)];
      eA[k * 16 + 0] = (float)(a0 * a0); eA[k * 16 + 1] = (float)(a1 * a1);
      eB[k * 16 + 0] = (float)(c0 * c0); eB[k * 16 + 1] = (float)(c1 * c1);
      int pa = 0, pb = 0;
      unsigned char* myh = hist + tid * 76;
#pragma unroll
      for (int step = 0; step <= 16; ++step) {
        const int w = t0 + step;
        if (w < 4094) {
          double a2 = SRe[PHYS(w + 2)];
          double c2 = SIm[PHYS(w + 2)];
          if (step <= 13) {
            eA[k * 16 + step + 2] = (float)(a2 * a2);
            eB[k * 16 + step + 2] = (float)(c2 * c2);
          }
          int ia = (int)(a0 <= a1) | ((int)(a0 <= a2) << 1) | ((int)(a1 <= a2) << 2);
          int ca = (int)((537125u >> (3 * ia)) & 7u);
          int ib = (int)(c0 <= c1) | ((int)(c0 <= c2) << 1) | ((int)(c1 <= c2) << 2);
          int cb = (int)((537125u >> (3 * ib)) & 7u);
          if (step >= 1) { myh[pa * 6 + ca] += 1; myh[36 + pb * 6 + cb] += 1; }
          pa = ca; pb = cb;
          a0 = a1; a1 = a2; c0 = c1; c1 = c2;
        }
      }
    }
  }

  // ---- moments ----
  float acc[40];
#pragma unroll
  for (int k = 0; k < 5; ++k) {
    float sA = 0.f, sB = 0.f;
#pragma unroll
    for (int i = 0; i < 16; ++i) { sA += eA[k * 16 + i]; sB += eB[k * 16 + i]; }
    acc[k] = sA; acc[20 + k] = sB;
  }
  {
    int id5 = 5;
#pragma unroll
    for (int k = 0; k < 5; ++k)
#pragma unroll
      for (int l = k; l < 5; ++l) {
        float sA = 0.f, sB = 0.f;
#pragma unroll
        for (int i = 0; i < 16; ++i) {
          sA += eA[k * 16 + i] * eA[l * 16 + i];
          sB += eB[k * 16 + i] * eB[l * 16 + i];
        }
        acc[id5] = sA; acc[20 + id5] = sB; ++id5;
      }
  }
  const int lane = tid & 63, wv = tid >> 6;
#pragma unroll
  for (int j = 0; j < 40; ++j) {
    float v = acc[j];
    v += __shfl_down(v, 32, 64);
    v += __shfl_down(v, 16, 64);
    v += __shfl_down(v, 8, 64);
    v += __shfl_down(v, 4, 64);
    v += __shfl_down(v, 2, 64);
    v += __shfl_down(v, 1, 64);
    if (lane == 0) red[wv * 40 + j] = v;
  }
  __syncthreads();
  if (tid < 40) stats[tid] = red[tid] + red[40 + tid] + red[80 + tid] + red[120 + tid];
  if (tid < 72) {
    unsigned int s = 0;
    for (int i = 0; i < 256; ++i) s += (unsigned int)hist[i * 76 + tid];
    histf[tid] = s;
  }
  __syncthreads();
  if (tid < 12) {
    int base0 = (tid < 6 ? 0 : 36) + (tid % 6) * 6;
    float rs = (float)(histf[base0] + histf[base0 + 1] + histf[base0 + 2] +
                       histf[base0 + 3] + histf[base0 + 4] + histf[base0 + 5]);
    rowinv[tid] = rs > 0.f ? 1.0f / rs : 1.0f;
  }
  __syncthreads();

  float* oA = out + (size_t)(b * 64 + dA) * 46;
  float* oB = oA + 46;
  if (tid < 36) oA[tid] = (float)histf[tid] * rowinv[tid / 6];
  if (tid >= 64 && tid < 100) {
    int j = tid - 64;
    oB[j] = (float)histf[36 + j] * rowinv[6 + j / 6];
  }
  if (tid >= 128 && tid < 138) corr_write(oA, stats, tid - 128);
  if (tid >= 160 && tid < 170) corr_write(oB, stats + 20, tid - 160);
}

// ---------------- launch ----------------
extern "C" void kernel_launch(void* const* d_in, const int* in_sizes, int n_in,
                              void* d_out, int out_size, void* d_ws, size_t ws_size,
                              hipStream_t stream) {
  (void)in_sizes; (void)n_in; (void)out_size;
  const float* x = (const float*)d_in[0];
  float* out = (float*)d_out;
  char* ws = (char*)d_ws;

  double2* Wt = (double2*)ws;                    // 64 KB
  double* Mdr = (double*)(ws + 65536);           // 160 KB
  float* xT = (float*)(ws + 262144);             // 16 MB
  int use_xt = (ws_size >= (size_t)(262144 + 16 * 64 * 4096 * 4)) ? 1 : 0;

  hipFuncSetAttribute(reinterpret_cast<const void*>(tf_main),
                      hipFuncAttributeMaxDynamicSharedMemorySize, SMEM_BYTES);

  tables_k<<<16, NTH, 0, stream>>>(Wt, Mdr);
  if (use_xt) transpose_k<<<1024, NTH, 0, stream>>>(x, xT);
  tf_main<<<512, NTH, SMEM_BYTES, stream>>>(x, xT, use_xt, Wt, Mdr, out);
}

// Round 3
// 185.060 us; speedup vs baseline: 1.0889x; 1.0889x over previous
//
#include <hip/hip_runtime.h>
#include <math.h>

// f32 pipeline: per (b,d-pair) 4096-pt single-precision FFT (twiddles & mask
// computed in f64 on device, stored f32) -> mask -> inverse FFT -> ordinal
// patterns + energy moments. Two d-series packed as one complex FFT (mask is
// real+even so Re/Im stay separable). f64->f32 switch: LDS 90.9->55.4 KB
// (1 -> 2 blocks/CU), f64 VALU is half-rate, and f32 kills the 4-way LDS
// bank conflicts from 2-bank-wide doubles.

#define NTH 256
#define PHYS(i) ((i) + ((i) >> 4))

// ---------------- table setup kernel ----------------
__device__ __forceinline__ float mask_f32(int k, int j) {
  // replicate reference: freqs=fftfreq(4096).astype(f32), centers f32, /0.2f, expf
  float f = (float)((j < 2048) ? j : (j - 4096)) * (1.0f / 4096.0f);
  float c = ((float)k - 2.5f) / 5.0f;
  float df = fabsf(f - c);
  float q = df / 0.2f;
  return expf(-0.5f * (q * q));
}

__global__ void tables_k(float2* __restrict__ Wt, float* __restrict__ Mdr) {
  int j = blockIdx.x * NTH + threadIdx.x;   // 0..4095
  double ang = -(2.0 * 3.14159265358979323846 / 4096.0) * (double)j;
  double s, c;
  sincos(ang, &s, &c);
  Wt[j] = make_float2((float)c, (float)s);
  int jr = (int)(__brev((unsigned)j) >> 20);      // bitrev12
  int jrn = (4096 - jr) & 4095;
#pragma unroll
  for (int k = 0; k < 5; ++k) {
    float m1 = mask_f32(k, jr);
    float m2 = mask_f32(k, jrn);
    // even-symmetrized mask (f64) with ifft 1/N folded in, stored f32
    Mdr[k * 4096 + j] = (float)(((double)m1 + (double)m2) * (0.5 / 4096.0));
  }
}

// ---------------- transpose (B,T,D) -> (B,D,T) ----------------
__global__ void transpose_k(const float* __restrict__ x, float* __restrict__ xT) {
  __shared__ float tile[64][65];
  int bb = blockIdx.x >> 6;
  int tt = blockIdx.x & 63;
  int lane = threadIdx.x & 63;
  int grp = threadIdx.x >> 6;
#pragma unroll
  for (int r = 0; r < 16; ++r) {
    int tl = grp + 4 * r;
    tile[tl][lane] = x[((size_t)bb * 4096 + tt * 64 + tl) * 64 + lane];
  }
  __syncthreads();
#pragma unroll
  for (int r = 0; r < 16; ++r) {
    int dl = grp + 4 * r;
    xT[((size_t)bb * 64 + dl) * 4096 + tt * 64 + lane] = tile[lane][dl];
  }
}

// ---------------- FFT building blocks (f32) ----------------
template <int S, bool INV>
__device__ __forceinline__ void fft_stage(float* __restrict__ SRe, float* __restrict__ SIm,
                                          const float2* __restrict__ Wt, int tid) {
  const int LOG = 9 - 3 * S;
  const int sub = 1 << LOG;
#pragma unroll
  for (int gi = 0; gi < 2; ++gi) {
    const int g = tid + 256 * gi;
    const int b_hi = g >> LOG;
    const int b_lo = g & (sub - 1);
    const int base = b_hi * (sub << 3) + b_lo;
    int idx[8];
    float ar[8], ai[8];
#pragma unroll
    for (int q = 0; q < 8; ++q) {
      idx[q] = PHYS(base + q * sub);
      ar[q] = SRe[idx[q]];
      ai[q] = SIm[idx[q]];
    }
    float2 t1[4], t2[2], t3;
#pragma unroll
    for (int q = 0; q < 4; ++q) t1[q] = Wt[(b_lo + q * sub) << (3 * S)];
    t2[0] = Wt[b_lo << (3 * S + 1)];
    t2[1] = Wt[(b_lo + sub) << (3 * S + 1)];
    t3 = Wt[b_lo << (3 * S + 2)];
    if (!INV) {
#pragma unroll
      for (int q = 0; q < 4; ++q) {
        float ur = ar[q] - ar[q + 4], ui = ai[q] - ai[q + 4];
        ar[q] += ar[q + 4]; ai[q] += ai[q + 4];
        ar[q + 4] = ur * t1[q].x - ui * t1[q].y;
        ai[q + 4] = ur * t1[q].y + ui * t1[q].x;
      }
#pragma unroll
      for (int h = 0; h < 8; h += 4)
#pragma unroll
        for (int qq = 0; qq < 2; ++qq) {
          int q = h + qq;
          float ur = ar[q] - ar[q + 2], ui = ai[q] - ai[q + 2];
          ar[q] += ar[q + 2]; ai[q] += ai[q + 2];
          ar[q + 2] = ur * t2[qq].x - ui * t2[qq].y;
          ai[q + 2] = ur * t2[qq].y + ui * t2[qq].x;
        }
#pragma unroll
      for (int q = 0; q < 8; q += 2) {
        float ur = ar[q] - ar[q + 1], ui = ai[q] - ai[q + 1];
        ar[q] += ar[q + 1]; ai[q] += ai[q + 1];
        ar[q + 1] = ur * t3.x - ui * t3.y;
        ai[q + 1] = ur * t3.y + ui * t3.x;
      }
    } else {
#pragma unroll
      for (int q = 0; q < 8; q += 2) {
        float br = ar[q + 1] * t3.x + ai[q + 1] * t3.y;
        float bi = ai[q + 1] * t3.x - ar[q + 1] * t3.y;
        ar[q + 1] = ar[q] - br; ai[q + 1] = ai[q] - bi;
        ar[q] += br; ai[q] += bi;
      }
#pragma unroll
      for (int h = 0; h < 8; h += 4)
#pragma unroll
        for (int qq = 0; qq < 2; ++qq) {
          int q = h + qq;
          float br = ar[q + 2] * t2[qq].x + ai[q + 2] * t2[qq].y;
          float bi = ai[q + 2] * t2[qq].x - ar[q + 2] * t2[qq].y;
          ar[q + 2] = ar[q] - br; ai[q + 2] = ai[q] - bi;
          ar[q] += br; ai[q] += bi;
        }
#pragma unroll
      for (int q = 0; q < 4; ++q) {
        float br = ar[q + 4] * t1[q].x + ai[q + 4] * t1[q].y;
        float bi = ai[q + 4] * t1[q].x - ar[q + 4] * t1[q].y;
        ar[q + 4] = ar[q] - br; ai[q + 4] = ai[q] - bi;
        ar[q] += br; ai[q] += bi;
      }
    }
#pragma unroll
    for (int q = 0; q < 8; ++q) { SRe[idx[q]] = ar[q]; SIm[idx[q]] = ai[q]; }
  }
}

__device__ __forceinline__ void s3_fwd(float* ar, float* ai, const float2* __restrict__ Wt) {
  float2 t1[4];
#pragma unroll
  for (int q = 0; q < 4; ++q) t1[q] = Wt[q << 9];
  float2 t20 = Wt[0], t21 = Wt[1 << 10];
#pragma unroll
  for (int q = 0; q < 4; ++q) {
    float ur = ar[q] - ar[q + 4], ui = ai[q] - ai[q + 4];
    ar[q] += ar[q + 4]; ai[q] += ai[q + 4];
    ar[q + 4] = ur * t1[q].x - ui * t1[q].y;
    ai[q + 4] = ur * t1[q].y + ui * t1[q].x;
  }
#pragma unroll
  for (int h = 0; h < 8; h += 4)
#pragma unroll
    for (int qq = 0; qq < 2; ++qq) {
      int q = h + qq;
      float2 t = qq ? t21 : t20;
      float ur = ar[q] - ar[q + 2], ui = ai[q] - ai[q + 2];
      ar[q] += ar[q + 2]; ai[q] += ai[q + 2];
      ar[q + 2] = ur * t.x - ui * t.y;
      ai[q + 2] = ur * t.y + ui * t.x;
    }
#pragma unroll
  for (int q = 0; q < 8; q += 2) {
    float ur = ar[q] - ar[q + 1], ui = ai[q] - ai[q + 1];
    ar[q] += ar[q + 1]; ai[q] += ai[q + 1];
    ar[q + 1] = ur; ai[q + 1] = ui;
  }
}

__device__ __forceinline__ void s3_inv(float* ar, float* ai, const float2* __restrict__ Wt) {
  float2 t1[4];
#pragma unroll
  for (int q = 0; q < 4; ++q) t1[q] = Wt[q << 9];
  float2 t20 = Wt[0], t21 = Wt[1 << 10];
#pragma unroll
  for (int q = 0; q < 8; q += 2) {
    float br = ar[q + 1], bi = ai[q + 1];
    ar[q + 1] = ar[q] - br; ai[q + 1] = ai[q] - bi;
    ar[q] += br; ai[q] += bi;
  }
#pragma unroll
  for (int h = 0; h < 8; h += 4)
#pragma unroll
    for (int qq = 0; qq < 2; ++qq) {
      int q = h + qq;
      float2 t = qq ? t21 : t20;
      float br = ar[q + 2] * t.x + ai[q + 2] * t.y;
      float bi = ai[q + 2] * t.x - ar[q + 2] * t.y;
      ar[q + 2] = ar[q] - br; ai[q + 2] = ai[q] - bi;
      ar[q] += br; ai[q] += bi;
    }
#pragma unroll
  for (int q = 0; q < 4; ++q) {
    float br = ar[q + 4] * t1[q].x + ai[q + 4] * t1[q].y;
    float bi = ai[q + 4] * t1[q].x - ar[q + 4] * t1[q].y;
    ar[q + 4] = ar[q] - br; ai[q + 4] = ai[q] - bi;
    ar[q] += br; ai[q] += bi;
  }
}

__device__ __forceinline__ void corr_write(float* o, const float* st, int j) {
  const int k = (int)((440700928u >> (3 * j)) & 7u);
  const int l = (int)((611428561u >> (3 * j)) & 7u);
  const float Sk = st[k], Sl = st[l];
  const int offk = (k * (11 - k)) >> 1;
  const int offl = (l * (11 - l)) >> 1;
  const float Skl = st[5 + offk + (l - k)];
  const float Skk = st[5 + offk];
  const float Sll = st[5 + offl];
  const float invT = 1.0f / 4096.0f;
  float cov = Skl - Sk * Sl * invT;
  float vk = Skk - Sk * Sk * invT;
  float vl = Sll - Sl * Sl * invT;
  float dk = sqrtf(fmaxf(vk, 0.f)), dl = sqrtf(fmaxf(vl, 0.f));
  float den = dk * dl;
  float corr = den > 0.f ? cov / den : 0.f;
  o[36 + j] = fminf(1.f, fmaxf(-1.f, corr));
}

// ---------------- main kernel: one block per (b, d-pair) ----------------
__global__ __launch_bounds__(NTH, 2) void tf_main(const float* __restrict__ x,
                                                  const float* __restrict__ xT, int use_xt,
                                                  const float2* __restrict__ Wt,
                                                  const float* __restrict__ Mdr,
                                                  float* __restrict__ out) {
  __shared__ float SRe[4352];
  __shared__ float SIm[4352];
  __shared__ unsigned char hist[NTH * 76];
  __shared__ float red[4][40];
  __shared__ float stats[40];
  __shared__ unsigned int histf[72];
  __shared__ float rowinv[12];

  const int tid = threadIdx.x;
  const int beta = blockIdx.x;
  const int b = beta >> 5;
  const int dA = (beta & 31) * 2;

  {  // zero own hist slice (76 B, dword-aligned)
    unsigned int* hw = (unsigned int*)(hist + tid * 76);
#pragma unroll
    for (int i = 0; i < 19; ++i) hw[i] = 0u;
  }

  // ---- stage x (two series -> complex) ----
  if (use_xt) {
    const float4* ra = (const float4*)(xT + (size_t)(b * 64 + dA) * 4096);
    const float4* rb = (const float4*)(xT + (size_t)(b * 64 + dA + 1) * 4096);
    for (int t4 = tid; t4 < 1024; t4 += NTH) {
      float4 va = ra[t4], vb = rb[t4];
      int t = t4 * 4;
      SRe[PHYS(t)] = va.x;     SIm[PHYS(t)] = vb.x;
      SRe[PHYS(t + 1)] = va.y; SIm[PHYS(t + 1)] = vb.y;
      SRe[PHYS(t + 2)] = va.z; SIm[PHYS(t + 2)] = vb.z;
      SRe[PHYS(t + 3)] = va.w; SIm[PHYS(t + 3)] = vb.w;
    }
  } else {
    const float2* xp = (const float2*)(x + (size_t)b * 4096 * 64 + dA);
    for (int t = tid; t < 4096; t += NTH) {
      float2 v = xp[(size_t)t * 32];
      SRe[PHYS(t)] = v.x;
      SIm[PHYS(t)] = v.y;
    }
  }
  __syncthreads();

  // ---- forward FFT: stages s=0..2 in LDS, s=3 in regs ----
  fft_stage<0, false>(SRe, SIm, Wt, tid); __syncthreads();
  fft_stage<1, false>(SRe, SIm, Wt, tid); __syncthreads();
  fft_stage<2, false>(SRe, SIm, Wt, tid); __syncthreads();

  float Fr[16], Fi[16];
#pragma unroll
  for (int j = 0; j < 16; ++j) {
    int p = PHYS(tid * 16 + j);
    Fr[j] = SRe[p]; Fi[j] = SIm[p];
  }
  s3_fwd(&Fr[0], &Fi[0], Wt);
  s3_fwd(&Fr[8], &Fi[8], Wt);
  // Fr/Fi hold spectrum at bit-reversed slots [16*tid, 16*tid+16)

  float eA[80], eB[80];

#pragma unroll
  for (int k = 0; k < 5; ++k) {
    float Zr[16], Zi[16];
#pragma unroll
    for (int j = 0; j < 16; ++j) {
      float m = Mdr[k * 4096 + tid * 16 + j];
      Zr[j] = Fr[j] * m; Zi[j] = Fi[j] * m;
    }
    s3_inv(&Zr[0], &Zi[0], Wt);
    s3_inv(&Zr[8], &Zi[8], Wt);
    __syncthreads();  // previous band's readers done before overwrite
#pragma unroll
    for (int j = 0; j < 16; ++j) {
      int p = PHYS(tid * 16 + j);
      SRe[p] = Zr[j]; SIm[p] = Zi[j];
    }
    __syncthreads();
    fft_stage<2, true>(SRe, SIm, Wt, tid); __syncthreads();
    fft_stage<1, true>(SRe, SIm, Wt, tid); __syncthreads();
    fft_stage<0, true>(SRe, SIm, Wt, tid); __syncthreads();
    // SRe[t] = modes_a[t], SIm[t] = modes_b[t] (natural order)

    // ---- band pass: ordinal patterns + energy stash ----
    {
      const int t0 = tid * 16;
      float a0 = SRe[PHYS(t0)], a1 = SRe[PHYS(t0 + 1)];
      float c0 = SIm[PHYS(t0)], c1 = SIm[PHYS(t0 + 1)];
      eA[k * 16 + 0] = a0 * a0; eA[k * 16 + 1] = a1 * a1;
      eB[k * 16 + 0] = c0 * c0; eB[k * 16 + 1] = c1 * c1;
      int pa = 0, pb = 0;
      unsigned char* myh = hist + tid * 76;
#pragma unroll
      for (int step = 0; step <= 16; ++step) {
        const int w = t0 + step;
        if (w < 4094) {
          float a2 = SRe[PHYS(w + 2)];
          float c2 = SIm[PHYS(w + 2)];
          if (step <= 13) {
            eA[k * 16 + step + 2] = a2 * a2;
            eB[k * 16 + step + 2] = c2 * c2;
          }
          int ia = (int)(a0 <= a1) | ((int)(a0 <= a2) << 1) | ((int)(a1 <= a2) << 2);
          int ca = (int)((537125u >> (3 * ia)) & 7u);
          int ib = (int)(c0 <= c1) | ((int)(c0 <= c2) << 1) | ((int)(c1 <= c2) << 2);
          int cb = (int)((537125u >> (3 * ib)) & 7u);
          if (step >= 1) { myh[pa * 6 + ca] += 1; myh[36 + pb * 6 + cb] += 1; }
          pa = ca; pb = cb;
          a0 = a1; a1 = a2; c0 = c1; c1 = c2;
        }
      }
    }
  }

  // ---- moments ----
  float acc[40];
#pragma unroll
  for (int k = 0; k < 5; ++k) {
    float sA = 0.f, sB = 0.f;
#pragma unroll
    for (int i = 0; i < 16; ++i) { sA += eA[k * 16 + i]; sB += eB[k * 16 + i]; }
    acc[k] = sA; acc[20 + k] = sB;
  }
  {
    int id5 = 5;
#pragma unroll
    for (int k = 0; k < 5; ++k)
#pragma unroll
      for (int l = k; l < 5; ++l) {
        float sA = 0.f, sB = 0.f;
#pragma unroll
        for (int i = 0; i < 16; ++i) {
          sA += eA[k * 16 + i] * eA[l * 16 + i];
          sB += eB[k * 16 + i] * eB[l * 16 + i];
        }
        acc[id5] = sA; acc[20 + id5] = sB; ++id5;
      }
  }
  const int lane = tid & 63, wv = tid >> 6;
#pragma unroll
  for (int j = 0; j < 40; ++j) {
    float v = acc[j];
    v += __shfl_down(v, 32, 64);
    v += __shfl_down(v, 16, 64);
    v += __shfl_down(v, 8, 64);
    v += __shfl_down(v, 4, 64);
    v += __shfl_down(v, 2, 64);
    v += __shfl_down(v, 1, 64);
    if (lane == 0) red[wv][j] = v;
  }
  __syncthreads();
  if (tid < 40) stats[tid] = red[0][tid] + red[1][tid] + red[2][tid] + red[3][tid];
  if (tid < 72) {
    unsigned int s = 0;
    for (int i = 0; i < 256; ++i) s += (unsigned int)hist[i * 76 + tid];
    histf[tid] = s;
  }
  __syncthreads();
  if (tid < 12) {
    int base0 = (tid < 6 ? 0 : 36) + (tid % 6) * 6;
    float rs = (float)(histf[base0] + histf[base0 + 1] + histf[base0 + 2] +
                       histf[base0 + 3] + histf[base0 + 4] + histf[base0 + 5]);
    rowinv[tid] = rs > 0.f ? 1.0f / rs : 1.0f;
  }
  __syncthreads();

  float* oA = out + (size_t)(b * 64 + dA) * 46;
  float* oB = oA + 46;
  if (tid < 36) oA[tid] = (float)histf[tid] * rowinv[tid / 6];
  if (tid >= 64 && tid < 100) {
    int j = tid - 64;
    oB[j] = (float)histf[36 + j] * rowinv[6 + j / 6];
  }
  if (tid >= 128 && tid < 138) corr_write(oA, stats, tid - 128);
  if (tid >= 160 && tid < 170) corr_write(oB, stats + 20, tid - 160);
}

// ---------------- launch ----------------
extern "C" void kernel_launch(void* const* d_in, const int* in_sizes, int n_in,
                              void* d_out, int out_size, void* d_ws, size_t ws_size,
                              hipStream_t stream) {
  (void)in_sizes; (void)n_in; (void)out_size;
  const float* x = (const float*)d_in[0];
  float* out = (float*)d_out;
  char* ws = (char*)d_ws;

  float2* Wt = (float2*)ws;                      // 32 KB
  float* Mdr = (float*)(ws + 32768);             // 80 KB
  float* xT = (float*)(ws + 131072);             // 16 MB
  int use_xt = (ws_size >= (size_t)(131072 + 16 * 64 * 4096 * 4)) ? 1 : 0;

  tables_k<<<16, NTH, 0, stream>>>(Wt, Mdr);
  if (use_xt) transpose_k<<<1024, NTH, 0, stream>>>(x, xT);
  tf_main<<<512, NTH, 0, stream>>>(x, xT, use_xt, Wt, Mdr, out);
}